// Round 5
// baseline (438.533 us; speedup 1.0000x reference)
//
#include <hip/hip_runtime.h>

// DelayBuffer: embeddings [B=4, S=4096, D=1024] f32.
// out[b, t, di*D + c] = emb[b, t - d, c] if t >= d else emb[b, t, c],  d = 1<<di.
//
// SCATTER formulation: one block per 8 INPUT rows. Reads each row exactly once
// (67 MB compulsory reads), stores to every output row that needs it:
//   - out[b, t+d, di]  for t+d < S   (shifted copy)
//   - out[b, t,   di]  for t < d     (boundary passthrough)
// Every output row written exactly once; all stores contiguous 4 KB rows.
// Branch conditions block-uniform in t -> no divergence.
//
// R5 changes vs R4: (1) REGULAR stores (NT stores suspected of throttling the
// write path; the harness's 1.6 GB fill hits 6.4 TB/s with regular stores).
// (2) 8 rows loaded up-front per block (compile-time trip count, 32 VGPRs of
// payload) -> 8 KB in flight per wave instead of 1 KB.

using f32x4 = __attribute__((ext_vector_type(4))) float;

constexpr unsigned B  = 4;
constexpr unsigned S  = 4096;          // power of two
constexpr unsigned ND = 6;             // delays d = 1<<di, di in [0,6)
constexpr unsigned D4 = 1024 / 4;      // f32x4 per row = 256
constexpr unsigned NROWS = B * S;      // 16384 input rows
constexpr unsigned RPB   = 8;          // rows per block
constexpr unsigned NBLK  = NROWS / RPB;// 2048 blocks

__global__ __launch_bounds__(256) void delay_scatter(
    const f32x4* __restrict__ in, f32x4* __restrict__ out) {
    const unsigned tid  = threadIdx.x;
    const unsigned row0 = blockIdx.x * RPB;

    // Load all 8 rows first — independent loads, deep memory-level parallelism.
    f32x4 v[RPB];
    #pragma unroll
    for (unsigned r = 0; r < RPB; ++r)
        v[r] = __builtin_nontemporal_load(&in[(size_t)(row0 + r) * D4 + tid]);

    #pragma unroll
    for (unsigned r = 0; r < RPB; ++r) {
        const unsigned row = row0 + r;
        const unsigned t   = row & (S - 1);
        const size_t   ob  = (size_t)row * (ND * D4) + tid;   // out row (b,t), di=0
        #pragma unroll
        for (unsigned di = 0; di < ND; ++di) {
            const unsigned d = 1u << di;
            if (t + d < S)   // out[b, t+d, di] = emb[b, t]
                out[ob + (size_t)(d * ND + di) * D4] = v[r];
            if (t < d)       // out[b, t, di] = emb[b, t]  (boundary passthrough)
                out[ob + (size_t)di * D4] = v[r];
        }
    }
}

extern "C" void kernel_launch(void* const* d_in, const int* in_sizes, int n_in,
                              void* d_out, int out_size, void* d_ws, size_t ws_size,
                              hipStream_t stream) {
    const f32x4* in  = (const f32x4*)d_in[0];
    f32x4*       out = (f32x4*)d_out;

    delay_scatter<<<NBLK, 256, 0, stream>>>(in, out);
}